// Round 1
// 1379.588 us; speedup vs baseline: 6.6446x; 6.6446x over previous
//
#include <hip/hip_runtime.h>
#include <cstdint>
#include <cstddef>

typedef unsigned short u16;
typedef short s8v __attribute__((ext_vector_type(8)));
typedef float f4v __attribute__((ext_vector_type(4)));

static __device__ __forceinline__ u16 f2bf(float x) {
  union { float f; uint32_t u; } v; v.f = x;
  uint32_t r = v.u + 0x7fffu + ((v.u >> 16) & 1u);   // RNE
  return (u16)(r >> 16);
}
static __device__ __forceinline__ float sigm(float x) { return 1.0f / (1.0f + __expf(-x)); }

// ---------------- prep: bf16 conversions + emb gather + bias sum ----------------
__global__ void kPrep(const float* __restrict__ fcW, const float* __restrict__ attnW,
                      const float* __restrict__ Wih, const float* __restrict__ bih,
                      const float* __restrict__ bhh, const float* __restrict__ embW,
                      const int* __restrict__ decX,
                      u16* __restrict__ fcWb, u16* __restrict__ attnWb, u16* __restrict__ Wihb,
                      u16* __restrict__ embg, float* __restrict__ biassum) {
  const long NF = 16384000L, NA = 524288L, NW = 524288L, NE = 524288L, NB = 2048L;
  const long total = NF + NA + NW + NE + NB;
  for (long i = (long)blockIdx.x * blockDim.x + threadIdx.x; i < total;
       i += (long)gridDim.x * blockDim.x) {
    if (i < NF) {
      fcWb[i] = f2bf(fcW[i]);
    } else if (i < NF + NA) {
      long k = i - NF; attnWb[k] = f2bf(attnW[k]);
    } else if (i < NF + NA + NW) {
      long k = i - NF - NA; Wihb[k] = f2bf(Wih[k]);
    } else if (i < NF + NA + NW + NE) {
      long k = i - NF - NA - NW;
      int row = (int)(k >> 8), e = (int)(k & 255);   // row = t*32+b
      int t = row >> 5, b = row & 31;
      int x = decX[b * 64 + t];
      embg[k] = f2bf(embW[(long)x * 256 + e]);       // emb_W[0] is all-zero => padding ok
    } else {
      long k = i - NF - NA - NW - NE;
      biassum[k] = bih[k] + bhh[k];
    }
  }
}

// ---------------- templated bf16 MFMA GEMM: C[M,N] = A[M,K] * B[N,K]^T + bias ----------------
// BM=BN=128, BK=32, 256 threads (4 waves, 2x2), 16x16x32 MFMA, frag-major LDS staging.
template <int ACT, int OUTBF>
__global__ __launch_bounds__(256) void kGemm(const u16* __restrict__ A, const u16* __restrict__ Bm,
                                             const float* __restrict__ bias,
                                             float* __restrict__ Cf, u16* __restrict__ Cb,
                                             int N, int K) {
  __shared__ u16 lA[8 * 64 * 8];
  __shared__ u16 lB[8 * 64 * 8];
  const int tid = threadIdx.x;
  const int m0 = blockIdx.x * 128, n0 = blockIdx.y * 128;
  const int lane = tid & 63, wid = tid >> 6;
  const int wm = wid >> 1, wn = wid & 1;
  f4v acc[4][4] = {};
  const int nkt = K >> 5;
  for (int kt = 0; kt < nkt; ++kt) {
    const int k0 = kt << 5;
#pragma unroll
    for (int i = 0; i < 2; ++i) {
      int u = i * 256 + tid;
      int m = u >> 2, q = u & 3;
      uint4 va = *(const uint4*)(A + (size_t)(m0 + m) * K + k0 + q * 8);
      *(uint4*)&lA[(((m >> 4) * 64) + q * 16 + (m & 15)) * 8] = va;
      uint4 vb = *(const uint4*)(Bm + (size_t)(n0 + m) * K + k0 + q * 8);
      *(uint4*)&lB[(((m >> 4) * 64) + q * 16 + (m & 15)) * 8] = vb;
    }
    __syncthreads();
    s8v af[4], bfr[4];
#pragma unroll
    for (int i = 0; i < 4; ++i) af[i] = *(const s8v*)&lA[((wm * 4 + i) * 64 + lane) * 8];
#pragma unroll
    for (int j = 0; j < 4; ++j) bfr[j] = *(const s8v*)&lB[((wn * 4 + j) * 64 + lane) * 8];
#pragma unroll
    for (int i = 0; i < 4; ++i)
#pragma unroll
      for (int j = 0; j < 4; ++j)
        acc[i][j] = __builtin_amdgcn_mfma_f32_16x16x32_bf16(af[i], bfr[j], acc[i][j], 0, 0, 0);
    __syncthreads();
  }
  const int rq = lane >> 4, cl = lane & 15;
#pragma unroll
  for (int j = 0; j < 4; ++j) {
    int col = n0 + wn * 64 + j * 16 + cl;
    float bv = bias[col];
#pragma unroll
    for (int i = 0; i < 4; ++i) {
      int rowb = m0 + wm * 64 + i * 16 + rq * 4;
      f4v v = acc[i][j];
#pragma unroll
      for (int r = 0; r < 4; ++r) {
        float x = v[r] + bv;
        if (ACT) x = tanhf(x);
        size_t off = (size_t)(rowb + r) * N + col;
        if (OUTBF) Cb[off] = f2bf(x); else Cf[off] = x;
      }
    }
  }
}

// ---------------- one LSTM timestep, parallelized over all 256 CUs ----------------
// Grid = 256 blocks; block bx owns h-columns j0=bx*2, j0+1 (=> 8 gate rows of Whh).
// Thread (bg=tid>>5 -> 4 batches, ks=tid&31 -> interleaved k4 slices).
// Kernel boundary between timesteps IS the grid-wide barrier.
__global__ __launch_bounds__(256) void kStep(const float* __restrict__ Gpre,
                                             const float* __restrict__ Whh,
                                             const float* __restrict__ hprev,
                                             float* __restrict__ hout,
                                             const float* __restrict__ cin,
                                             float* __restrict__ cout,
                                             float* __restrict__ hext,
                                             float* __restrict__ cext,
                                             int t, int last) {
  __shared__ float hsh[32 * 512];          // 64 KB: h_{t-1} for all 32 batch rows
  const int tid = threadIdx.x;
  const int j0 = blockIdx.x * 2;
  // stage h_{t-1}: fully coalesced, 16 float4 per thread
  {
    const float4* src = (const float4*)hprev;
    float4* dst = (float4*)hsh;
#pragma unroll
    for (int i = 0; i < 16; ++i) { int idx = i * 256 + tid; dst[idx] = src[idx]; }
  }
  __syncthreads();
  const int bg = tid >> 5;                 // batch group: b = bg*4 + bb
  const int ks = tid & 31;                 // k4 = ks + 32*c  (interleaved -> contiguous lanes)
  float acc[4][8];                         // [bb][r], r = gate*2 + jj
#pragma unroll
  for (int bb = 0; bb < 4; ++bb)
#pragma unroll
    for (int r = 0; r < 8; ++r) acc[bb][r] = 0.f;
#pragma unroll
  for (int c = 0; c < 4; ++c) {
    const int k4 = ks + 32 * c;
    float4 w4[8];
#pragma unroll
    for (int r = 0; r < 8; ++r) {
      const int row = (r >> 1) * 512 + j0 + (r & 1);
      w4[r] = *(const float4*)&Whh[(size_t)row * 512 + (size_t)k4 * 4];  // 512B/32 lanes, L2-hot
    }
#pragma unroll
    for (int bb = 0; bb < 4; ++bb) {
      const int b = bg * 4 + bb;
      float4 h4 = *(const float4*)&hsh[b * 512 + k4 * 4];
#pragma unroll
      for (int r = 0; r < 8; ++r)
        acc[bb][r] += w4[r].x * h4.x + w4[r].y * h4.y + w4[r].z * h4.z + w4[r].w * h4.w;
    }
  }
  // butterfly reduce over the 32 k-slices (lane bits 0..4; bg lives in bit 5)
#pragma unroll
  for (int off = 1; off < 32; off <<= 1)
#pragma unroll
    for (int bb = 0; bb < 4; ++bb)
#pragma unroll
      for (int r = 0; r < 8; ++r)
        acc[bb][r] += __shfl_xor(acc[bb][r], off, 64);
  if (ks == 0) {
#pragma unroll
    for (int bb = 0; bb < 4; ++bb) {
      const int b = bg * 4 + bb;
      const float* gp = Gpre + ((size_t)t * 32 + b) * 2048;
#pragma unroll
      for (int jj = 0; jj < 2; ++jj) {
        const int j = j0 + jj;
        float iv = sigm(acc[bb][0 + jj] + gp[j]);
        float fv = sigm(acc[bb][2 + jj] + gp[512 + j]);
        float gv = tanhf(acc[bb][4 + jj] + gp[1024 + j]);
        float ov = sigm(acc[bb][6 + jj] + gp[1536 + j]);
        float cv = fv * cin[b * 512 + j] + iv * gv;
        float hv = ov * tanhf(cv);
        cout[b * 512 + j] = cv;
        hout[b * 512 + j] = hv;
        if (last) { hext[b * 512 + j] = hv; cext[b * 512 + j] = cv; }
      }
    }
  }
}

// ---------------- attention: scores -> softmax -> context; emit CAT=[h|c_t] in bf16 ----------
__global__ __launch_bounds__(256) void kAttn(const float* __restrict__ Hall, const float* __restrict__ enc,
                                             u16* __restrict__ CAT) {
  const int bx = blockIdx.x;
  const int b = bx >> 3, tg = bx & 7;     // 8 timesteps per block
  const int tid = threadIdx.x;
  __shared__ float sh[8][516];
  __shared__ float sa[8][132];
  __shared__ float red[8][32];
  for (int tt = 0; tt < 8; ++tt) {
    int t = tg * 8 + tt;
    const float* hr = Hall + ((size_t)t * 32 + b) * 512;
    u16* cr = CAT + ((size_t)(b * 64 + t)) * 1024;
    for (int k = tid; k < 512; k += 256) { float v = hr[k]; sh[tt][k] = v; cr[k] = f2bf(v); }
  }
  __syncthreads();
  {  // scores: thread = (t_local = tid&7, e_base = tid>>3)
    const int tl = tid & 7, eb = tid >> 3;
#pragma unroll
    for (int u = 0; u < 4; ++u) {
      int e = eb + u * 32;
      const float* er = enc + ((size_t)b * 128 + e) * 512;
      float a = 0.f;
      for (int k = 0; k < 512; k += 4) {
        float4 ev = *(const float4*)&er[k];
        float4 hv = *(const float4*)&sh[tl][k];
        a += ev.x * hv.x + ev.y * hv.y + ev.z * hv.z + ev.w * hv.w;
      }
      sa[tl][e] = a;
    }
  }
  __syncthreads();
  {  // softmax over 128 per t: thread = (g = tid>>5, l = tid&31)
    const int g = tid >> 5, l = tid & 31;
    float mx = -1e30f;
#pragma unroll
    for (int u = 0; u < 4; ++u) mx = fmaxf(mx, sa[g][l + u * 32]);
    red[g][l] = mx;
    __syncthreads();
    if (l == 0) {
      float m2 = -1e30f;
      for (int i = 0; i < 32; ++i) m2 = fmaxf(m2, red[g][i]);
      sa[g][128] = m2;
    }
    __syncthreads();
    float m2 = sa[g][128];
    float s = 0.f;
#pragma unroll
    for (int u = 0; u < 4; ++u) { int e = l + u * 32; float p = __expf(sa[g][e] - m2); sa[g][e] = p; s += p; }
    red[g][l] = s;
    __syncthreads();
    if (l == 0) {
      float s2 = 0.f;
      for (int i = 0; i < 32; ++i) s2 += red[g][i];
      sa[g][129] = 1.0f / s2;
    }
    __syncthreads();
    float inv = sa[g][129];
#pragma unroll
    for (int u = 0; u < 4; ++u) sa[g][l + u * 32] *= inv;
  }
  __syncthreads();
  {  // context: thread covers cols 2*tid, 2*tid+1 for all 8 t
    float a0[8], a1[8];
#pragma unroll
    for (int tt = 0; tt < 8; ++tt) { a0[tt] = 0.f; a1[tt] = 0.f; }
    const float* eb2 = enc + (size_t)b * 128 * 512 + tid * 2;
    for (int e = 0; e < 128; ++e) {
      float2 v = *(const float2*)&eb2[(size_t)e * 512];
#pragma unroll
      for (int tt = 0; tt < 8; ++tt) { float a = sa[tt][e]; a0[tt] += a * v.x; a1[tt] += a * v.y; }
    }
#pragma unroll
    for (int tt = 0; tt < 8; ++tt) {
      int t = tg * 8 + tt;
      u16* cr = CAT + ((size_t)(b * 64 + t)) * 1024 + 512;
      cr[tid * 2] = f2bf(a0[tt]); cr[tid * 2 + 1] = f2bf(a1[tt]);
    }
  }
}

// ---------------- launcher ----------------
extern "C" void kernel_launch(void* const* d_in, const int* in_sizes, int n_in,
                              void* d_out, int out_size, void* d_ws, size_t ws_size,
                              hipStream_t stream) {
  const int*   decX  = (const int*)d_in[0];
  const float* enc   = (const float*)d_in[1];
  const float* h0    = (const float*)d_in[2];
  const float* c0    = (const float*)d_in[3];
  const float* embW  = (const float*)d_in[4];
  const float* Wih   = (const float*)d_in[5];
  const float* Whh   = (const float*)d_in[6];
  const float* bih   = (const float*)d_in[7];
  const float* bhh   = (const float*)d_in[8];
  const float* attnW = (const float*)d_in[9];
  const float* attnb = (const float*)d_in[10];
  const float* fcW   = (const float*)d_in[11];
  const float* fcb   = (const float*)d_in[12];
  float* out = (float*)d_out;

  char* ws = (char*)d_ws;
  u16*   fcWb    = (u16*)(ws);                    // 32,768,000 B
  u16*   attnWb  = (u16*)(ws + 32768000);         //  1,048,576 B
  u16*   Wihb    = (u16*)(ws + 33816576);         //  1,048,576 B
  u16*   embg    = (u16*)(ws + 34865152);         //  1,048,576 B (dead after GEMM#1)
  float* biassum = (float*)(ws + 35913728);       //      8,192 B
  float* Gpre    = (float*)(ws + 35921920);       // 16,777,216 B
  float* Hall    = (float*)(ws + 52699136);       //  4,194,304 B
  u16*   CAT     = (u16*)(ws + 56893440);         //  4,194,304 B
  u16*   OUTb    = (u16*)(ws + 61087744);         //  2,097,152 B  (total ~63.2 MB)
  float* cws     = (float*)embg;                  // reuse dead embg region: c-state 65,536 B

  hipLaunchKernelGGL(kPrep, dim3(4096), dim3(256), 0, stream,
                     fcW, attnW, Wih, bih, bhh, embW, decX, fcWb, attnWb, Wihb, embg, biassum);
  // G_pre[t*32+b][2048] = embg @ Wih^T + (b_ih+b_hh)
  hipLaunchKernelGGL((kGemm<0, 0>), dim3(16, 16), dim3(256), 0, stream,
                     embg, Wihb, biassum, Gpre, (u16*)nullptr, 2048, 256);
  // LSTM recurrence: 64 chained per-step launches; each parallelizes the
  // [32,512]@[512,2048] recurrent GEMM over 256 blocks. embg/cws reuse is safe:
  // embg is consumed by the GEMM above before the first kStep runs.
  float* hx = out + 65536000L;             // final h
  float* cx = out + 65536000L + 16384L;    // final c
  for (int t = 0; t < 64; ++t) {
    const float* hp = (t == 0) ? h0 : (Hall + (size_t)(t - 1) * 16384);
    const float* ci = (t == 0) ? c0 : cws;
    hipLaunchKernelGGL(kStep, dim3(256), dim3(256), 0, stream,
                       Gpre, Whh, hp, Hall + (size_t)t * 16384, ci, cws, hx, cx,
                       t, (int)(t == 63));
  }
  hipLaunchKernelGGL(kAttn, dim3(256), dim3(256), 0, stream, Hall, enc, CAT);
  // OUT[m][512] = tanh(CAT @ attnW^T + attn_b), bf16
  hipLaunchKernelGGL((kGemm<1, 1>), dim3(16, 4), dim3(256), 0, stream,
                     CAT, attnWb, attnb, (float*)nullptr, OUTb, 512, 1024);
  // logits[m][32000] = OUT @ fcW^T + fc_b  (m = b*64+t => contiguous [B,T,V] output)
  hipLaunchKernelGGL((kGemm<0, 0>), dim3(16, 250), dim3(256), 0, stream,
                     OUTb, fcWb, fcb, out, (u16*)nullptr, 32000, 512);
}